// Round 1
// baseline (57.605 us; speedup 1.0000x reference)
//
#include <hip/hip_runtime.h>
#include <math.h>

#define N    1024
#define FEAT 16
#define D    256
#define LOG2E 1.4426950408889634f

#if defined(__has_builtin)
#  if __has_builtin(__builtin_amdgcn_exp2f)
#    define EXP2(x) __builtin_amdgcn_exp2f(x)
#  else
#    define EXP2(x) exp2f(x)
#  endif
#else
#  define EXP2(x) exp2f(x)
#endif

// Block = (column k, half of the i-range). 256 threads.
// Phase 1: compute the full scaled column Ms[:,k]*log2e into LDS (each
//          thread does 4 dot-products of length 16).
// Phase 2: each thread accumulates out_T for 2 rows over all 1024 j.
__global__ __launch_bounds__(256) void pairwise_kernel(
    const float* __restrict__ x,      // [N][FEAT]
    const float* __restrict__ T,      // [FEAT][D]
    float* __restrict__ outT_t)       // [D][N]  (transposed)
{
    const int k    = blockIdx.x >> 1;
    const int half = blockIdx.x & 1;
    const int tid  = threadIdx.x;

    __shared__ float col[N];

    // T[:,k] is block-uniform -> scalar regs
    float tc[FEAT];
#pragma unroll
    for (int f = 0; f < FEAT; ++f) tc[f] = T[f * D + k];

    // fill the scaled column
#pragma unroll
    for (int ii = 0; ii < 4; ++ii) {
        const int i = ii * 256 + tid;
        const float4* xr = (const float4*)(x + i * FEAT);
        float4 a0 = xr[0], a1 = xr[1], a2 = xr[2], a3 = xr[3];
        float dot = 0.f;
        dot = fmaf(a0.x, tc[0],  dot); dot = fmaf(a0.y, tc[1],  dot);
        dot = fmaf(a0.z, tc[2],  dot); dot = fmaf(a0.w, tc[3],  dot);
        dot = fmaf(a1.x, tc[4],  dot); dot = fmaf(a1.y, tc[5],  dot);
        dot = fmaf(a1.z, tc[6],  dot); dot = fmaf(a1.w, tc[7],  dot);
        dot = fmaf(a2.x, tc[8],  dot); dot = fmaf(a2.y, tc[9],  dot);
        dot = fmaf(a2.z, tc[10], dot); dot = fmaf(a2.w, tc[11], dot);
        dot = fmaf(a3.x, tc[12], dot); dot = fmaf(a3.y, tc[13], dot);
        dot = fmaf(a3.z, tc[14], dot); dot = fmaf(a3.w, tc[15], dot);
        col[i] = dot * LOG2E;
    }
    __syncthreads();

    const int i0 = half * 512 + tid;
    const int i1 = i0 + 256;
    const float m0 = col[i0];
    const float m1 = col[i1];

    float acc0 = 0.f, acc1 = 0.f;
    for (int j = 0; j < N; j += 4) {
        const float4 c = *(const float4*)&col[j];   // uniform addr: broadcast
        float e0 = EXP2(-fabsf(m0 - c.x));
        float e1 = EXP2(-fabsf(m0 - c.y));
        float e2 = EXP2(-fabsf(m0 - c.z));
        float e3 = EXP2(-fabsf(m0 - c.w));
        acc0 += (e0 + e1) + (e2 + e3);              // tree add: precision + ILP
        float f0 = EXP2(-fabsf(m1 - c.x));
        float f1 = EXP2(-fabsf(m1 - c.y));
        float f2 = EXP2(-fabsf(m1 - c.z));
        float f3 = EXP2(-fabsf(m1 - c.w));
        acc1 += (f0 + f1) + (f2 + f3);
    }

    outT_t[k * N + i0] = acc0;   // coalesced along i
    outT_t[k * N + i1] = acc1;
}

// out[i] = sigmoid( x[i,:]·w[0:16] + out_T[i,:]·w[16:272] + b )
__global__ __launch_bounds__(256) void final_kernel(
    const float* __restrict__ x,       // [N][FEAT]
    const float* __restrict__ outT_t,  // [D][N]
    const float* __restrict__ w,       // [FEAT+D]
    const float* __restrict__ b,       // [1]
    float* __restrict__ out)           // [N]
{
    const int i = blockIdx.x * 256 + threadIdx.x;
    float logit = b[0];
#pragma unroll
    for (int f = 0; f < FEAT; ++f)
        logit = fmaf(x[i * FEAT + f], w[f], logit);
#pragma unroll 4
    for (int k = 0; k < D; ++k)
        logit = fmaf(outT_t[k * N + i], w[FEAT + k], logit);   // coalesced
    out[i] = 1.f / (1.f + EXP2(-logit * LOG2E));
}

extern "C" void kernel_launch(void* const* d_in, const int* in_sizes, int n_in,
                              void* d_out, int out_size, void* d_ws, size_t ws_size,
                              hipStream_t stream) {
    const float* x  = (const float*)d_in[0];
    const float* T  = (const float*)d_in[1];
    const float* w  = (const float*)d_in[2];
    const float* b  = (const float*)d_in[3];
    float* out      = (float*)d_out;
    float* outT_t   = (float*)d_ws;    // D*N floats = 1 MB

    pairwise_kernel<<<dim3(D * 2), dim3(256), 0, stream>>>(x, T, outT_t);
    final_kernel<<<dim3(N / 256), dim3(256), 0, stream>>>(x, outT_t, w, b, out);
}

// Round 2
// 21.308 us; speedup vs baseline: 2.7035x; 2.7035x over previous
//
#include <hip/hip_runtime.h>
#include <math.h>

#define N    1024
#define FEAT 16
#define D    256
#define LOG2E 1.4426950408889634f

#if defined(__has_builtin)
#  if __has_builtin(__builtin_amdgcn_exp2f)
#    define EXP2(x) __builtin_amdgcn_exp2f(x)
#  else
#    define EXP2(x) exp2f(x)
#  endif
#else
#  define EXP2(x) exp2f(x)
#endif

typedef unsigned long long u64;

// One block per column k. 512 threads.
//  Phase 1: compute u[i] = Ms[i,k]*log2e, pack (monotonic(u)<<32 | i) keys.
//  Phase 2: bitonic sort keys ascending (55 passes).
//  Phase 3: per sorted position r: ea=2^u, eb=2^-u into float2 scan array.
//  Phase 4: dual Hillis-Steele scan: A=prefix(ea) leftward, B=prefix(eb) rightward.
//  Phase 5: out[r] = eb*A[r] + ea*B[r] - 1; scatter to outT_t[k*N + orig_i].
__global__ __launch_bounds__(512) void column_kernel(
    const float* __restrict__ x,      // [N][FEAT]
    const float* __restrict__ T,      // [FEAT][D]
    float* __restrict__ outT_t)       // [D][N]
{
    const int k = blockIdx.x;
    const int t = threadIdx.x;

    __shared__ u64    keys[N];        // 8 KB
    __shared__ float2 AB[2][N];       // 16 KB (double-buffered dual scan)

    // ---- Phase 1: column values -> packed keys ----
    float tc[FEAT];
#pragma unroll
    for (int f = 0; f < FEAT; ++f) tc[f] = T[f * D + k];

#pragma unroll
    for (int half = 0; half < 2; ++half) {
        const int i = half * 512 + t;
        const float4* xr = (const float4*)(x + i * FEAT);
        float4 a0 = xr[0], a1 = xr[1], a2 = xr[2], a3 = xr[3];
        float dot = 0.f;
        dot = fmaf(a0.x, tc[0],  dot); dot = fmaf(a0.y, tc[1],  dot);
        dot = fmaf(a0.z, tc[2],  dot); dot = fmaf(a0.w, tc[3],  dot);
        dot = fmaf(a1.x, tc[4],  dot); dot = fmaf(a1.y, tc[5],  dot);
        dot = fmaf(a1.z, tc[6],  dot); dot = fmaf(a1.w, tc[7],  dot);
        dot = fmaf(a2.x, tc[8],  dot); dot = fmaf(a2.y, tc[9],  dot);
        dot = fmaf(a2.z, tc[10], dot); dot = fmaf(a2.w, tc[11], dot);
        dot = fmaf(a3.x, tc[12], dot); dot = fmaf(a3.y, tc[13], dot);
        dot = fmaf(a3.z, tc[14], dot); dot = fmaf(a3.w, tc[15], dot);
        const float u = dot * LOG2E;
        unsigned b    = __float_as_uint(u);
        unsigned mono = (b & 0x80000000u) ? ~b : (b | 0x80000000u);
        keys[i] = ((u64)mono << 32) | (unsigned)i;
    }

    // ---- Phase 2: bitonic sort (ascending) ----
    for (int size = 2; size <= N; size <<= 1) {
        for (int stride = size >> 1; stride > 0; stride >>= 1) {
            __syncthreads();
            const int lo  = ((t & ~(stride - 1)) << 1) | (t & (stride - 1));
            const int hi  = lo + stride;
            const bool asc = (lo & size) == 0;
            const u64 a = keys[lo];
            const u64 c = keys[hi];
            if ((a > c) == asc) { keys[lo] = c; keys[hi] = a; }
        }
    }
    __syncthreads();

    // ---- Phase 3: unpack + exp ----
    float ea_[2], eb_[2];
    int   oi_[2];
#pragma unroll
    for (int half = 0; half < 2; ++half) {
        const int r = half * 512 + t;
        const u64 key = keys[r];
        const unsigned mono = (unsigned)(key >> 32);
        const unsigned bits = (mono & 0x80000000u) ? (mono ^ 0x80000000u) : ~mono;
        const float u = __uint_as_float(bits);
        const float ea = EXP2(u);      // e^{Ms}
        const float eb = EXP2(-u);     // e^{-Ms}
        ea_[half] = ea; eb_[half] = eb;
        oi_[half] = (int)(key & 0xFFFFFFFFu);
        AB[0][r] = make_float2(ea, eb);
    }

    // ---- Phase 4: dual scan (A leftward prefix, B rightward prefix) ----
    int src = 0;
    for (int d = 1; d < N; d <<= 1) {
        __syncthreads();
#pragma unroll
        for (int half = 0; half < 2; ++half) {
            const int r = half * 512 + t;
            float2 s = AB[src][r];
            float ax = s.x + ((r >= d)    ? AB[src][r - d].x : 0.f);
            float by = s.y + ((r + d < N) ? AB[src][r + d].y : 0.f);
            AB[src ^ 1][r] = make_float2(ax, by);
        }
        src ^= 1;
    }
    __syncthreads();

    // ---- Phase 5: combine + scatter ----
#pragma unroll
    for (int half = 0; half < 2; ++half) {
        const int r = half * 512 + t;
        const float2 s = AB[src][r];
        const float o = fmaf(eb_[half], s.x, fmaf(ea_[half], s.y, -1.f));
        outT_t[k * N + oi_[half]] = o;
    }
}

// Stage B: partial weighted sums over k-chunks of 32.
// grid = 32 blocks: kblk = bid & 7, iblk = bid >> 3.
__global__ __launch_bounds__(256) void final_partial(
    const float* __restrict__ outT_t,  // [D][N]
    const float* __restrict__ w,       // [FEAT+D]
    float* __restrict__ part)          // [8][N]
{
    const int kblk = blockIdx.x & 7;
    const int iblk = blockIdx.x >> 3;
    const int i = iblk * 256 + threadIdx.x;
    float acc = 0.f;
    const int k0 = kblk * 32;
#pragma unroll 8
    for (int kk = 0; kk < 32; ++kk) {
        const int k = k0 + kk;
        acc = fmaf(outT_t[k * N + i], w[FEAT + k], acc);
    }
    part[kblk * N + i] = acc;
}

// Stage C: combine partials + x-dot + bias + sigmoid.
__global__ __launch_bounds__(256) void final_reduce(
    const float* __restrict__ x,       // [N][FEAT]
    const float* __restrict__ part,    // [8][N]
    const float* __restrict__ w,       // [FEAT+D]
    const float* __restrict__ b,       // [1]
    float* __restrict__ out)           // [N]
{
    const int i = blockIdx.x * 256 + threadIdx.x;
    float logit = b[0];
#pragma unroll
    for (int f = 0; f < FEAT; ++f)
        logit = fmaf(x[i * FEAT + f], w[f], logit);
#pragma unroll
    for (int kb = 0; kb < 8; ++kb)
        logit += part[kb * N + i];
    out[i] = 1.f / (1.f + EXP2(-logit * LOG2E));
}

extern "C" void kernel_launch(void* const* d_in, const int* in_sizes, int n_in,
                              void* d_out, int out_size, void* d_ws, size_t ws_size,
                              hipStream_t stream) {
    const float* x  = (const float*)d_in[0];
    const float* T  = (const float*)d_in[1];
    const float* w  = (const float*)d_in[2];
    const float* b  = (const float*)d_in[3];
    float* out      = (float*)d_out;
    float* outT_t   = (float*)d_ws;                 // D*N floats = 1 MB
    float* part     = (float*)d_ws + (size_t)D * N; // 8*N floats = 32 KB

    column_kernel<<<dim3(D), dim3(512), 0, stream>>>(x, T, outT_t);
    final_partial<<<dim3(32), dim3(256), 0, stream>>>(outT_t, w, part);
    final_reduce<<<dim3(N / 256), dim3(256), 0, stream>>>(x, part, w, b, out);
}

// Round 3
// 17.045 us; speedup vs baseline: 3.3795x; 1.2501x over previous
//
#include <hip/hip_runtime.h>
#include <math.h>

#define N    1024
#define FEAT 16
#define D    256
#define NB   512          // value buckets (== blockDim of column kernel)
#define LOG2E 1.4426950408889634f

#if defined(__has_builtin)
#  if __has_builtin(__builtin_amdgcn_exp2f)
#    define EXP2(x) __builtin_amdgcn_exp2f(x)
#  else
#    define EXP2(x) exp2f(x)
#  endif
#else
#  define EXP2(x) exp2f(x)
#endif

// One block per column k, 512 threads, 2 elements/thread.
// out[i] = sum_j exp(-|u_i - u_j|)  with u = Ms[:,k] (stored pre-scaled by
// log2(e) so every exponential is a raw v_exp_f32).
// Counting-sort by NB value buckets:
//   cross-bucket terms are EXACT via prefix/suffix sums of 2^u / 2^-u
//   (lower bucket  =>  u_j < u_i strictly, so exp(-|d|)=2^{u_j-u_i});
//   same-bucket terms brute-forced (avg ~4 members).
__global__ __launch_bounds__(512) void column_kernel(
    const float* __restrict__ x,      // [N][FEAT]
    const float* __restrict__ T,      // [FEAT][D]
    float* __restrict__ outT_t)       // [D][N]
{
    const int k = blockIdx.x;
    const int t = threadIdx.x;

    __shared__ float  su[N];          // bucket-compacted u values (4 KB)
    __shared__ int    hist[NB];
    __shared__ int    boff[NB];
    __shared__ int    ctr[NB];
    __shared__ float  Sx[NB], Sn[NB]; // per-bucket sums of 2^u, 2^-u
    __shared__ float2 scanF[2][NB];   // dual scan: .x fwd-incl(Sx), .y bwd-incl(Sn)
    __shared__ int    scanI[2][NB];   // fwd-incl scan of hist
    __shared__ float  red[16];
    __shared__ float  lohi[2];

    // zero-init (t covers 0..NB-1)
    hist[t] = 0; Sx[t] = 0.f; Sn[t] = 0.f;

    // ---- Phase 1: u values (pre-scaled by log2 e) ----
    float tc[FEAT];
#pragma unroll
    for (int f = 0; f < FEAT; ++f) tc[f] = T[f * D + k];

    float us[2];
#pragma unroll
    for (int half = 0; half < 2; ++half) {
        const int i = half * 512 + t;
        const float4* xr = (const float4*)(x + i * FEAT);
        float4 a0 = xr[0], a1 = xr[1], a2 = xr[2], a3 = xr[3];
        float dot = 0.f;
        dot = fmaf(a0.x, tc[0],  dot); dot = fmaf(a0.y, tc[1],  dot);
        dot = fmaf(a0.z, tc[2],  dot); dot = fmaf(a0.w, tc[3],  dot);
        dot = fmaf(a1.x, tc[4],  dot); dot = fmaf(a1.y, tc[5],  dot);
        dot = fmaf(a1.z, tc[6],  dot); dot = fmaf(a1.w, tc[7],  dot);
        dot = fmaf(a2.x, tc[8],  dot); dot = fmaf(a2.y, tc[9],  dot);
        dot = fmaf(a2.z, tc[10], dot); dot = fmaf(a2.w, tc[11], dot);
        dot = fmaf(a3.x, tc[12], dot); dot = fmaf(a3.y, tc[13], dot);
        dot = fmaf(a3.z, tc[14], dot); dot = fmaf(a3.w, tc[15], dot);
        us[half] = dot * LOG2E;
    }

    // ---- min/max reduce ----
    float mn = fminf(us[0], us[1]);
    float mx = fmaxf(us[0], us[1]);
#pragma unroll
    for (int m = 1; m < 64; m <<= 1) {
        mn = fminf(mn, __shfl_xor(mn, m));
        mx = fmaxf(mx, __shfl_xor(mx, m));
    }
    const int wid = t >> 6, lane = t & 63;
    if (lane == 0) { red[wid] = mn; red[8 + wid] = mx; }
    __syncthreads();                       // also covers zero-init
    if (t == 0) {
        float lo = red[0], hi = red[8];
#pragma unroll
        for (int w2 = 1; w2 < 8; ++w2) {
            lo = fminf(lo, red[w2]);
            hi = fmaxf(hi, red[8 + w2]);
        }
        lohi[0] = lo; lohi[1] = hi;
    }
    __syncthreads();
    const float lo    = lohi[0];
    const float range = lohi[1] - lo;
    const float invh  = (range > 1e-20f) ? ((float)NB / range) * (1.f - 4e-7f) : 0.f;

    // ---- Phase 2: bucket + histogram + per-bucket exp sums ----
    int   b_[2];
    float ea_[2], eb_[2];
#pragma unroll
    for (int half = 0; half < 2; ++half) {
        const float u = us[half];
        int b = (int)((u - lo) * invh);
        b = min(b, NB - 1);
        b_[half] = b;
        const float ea = EXP2(u);    // 2^{u_scaled} = e^{Ms}
        const float eb = EXP2(-u);
        ea_[half] = ea; eb_[half] = eb;
        atomicAdd(&hist[b], 1);
        atomicAdd(&Sx[b], ea);
        atomicAdd(&Sn[b], eb);
    }
    __syncthreads();

    // ---- Phase 3: fused scans over buckets (t == bucket index) ----
    scanF[0][t] = make_float2(Sx[t], Sn[t]);
    scanI[0][t] = hist[t];
    int src = 0;
    for (int d = 1; d < NB; d <<= 1) {
        __syncthreads();
        float2 s = scanF[src][t];
        int    c = scanI[src][t];
        if (t >= d)     { s.x += scanF[src][t - d].x; c += scanI[src][t - d]; }
        if (t + d < NB) { s.y += scanF[src][t + d].y; }
        scanF[src ^ 1][t] = s;
        scanI[src ^ 1][t] = c;
        src ^= 1;
    }
    __syncthreads();
    const int off = scanI[src][t] - hist[t];   // exclusive offset
    boff[t] = off;
    ctr[t]  = off;
    __syncthreads();

    // ---- Phase 4: scatter (within-bucket order arbitrary) ----
#pragma unroll
    for (int half = 0; half < 2; ++half) {
        const int p = atomicAdd(&ctr[b_[half]], 1);
        su[p] = us[half];
    }
    __syncthreads();

    // ---- Phase 5: combine ----
#pragma unroll
    for (int half = 0; half < 2; ++half) {
        const int   b  = b_[half];
        const float u  = us[half];
        const float P  = scanF[src][b].x - Sx[b];   // sum 2^{u_j}, lower buckets
        const float Q  = scanF[src][b].y - Sn[b];   // sum 2^{-u_j}, upper buckets
        float acc = fmaf(eb_[half], P, ea_[half] * Q);
        const int s = boff[b];
        const int e = s + hist[b];
        for (int p = s; p < e; ++p)
            acc += EXP2(-fabsf(u - su[p]));          // includes self: +1
        outT_t[k * N + (half * 512 + t)] = acc;
    }
}

// Fused fc + sigmoid. Grid 32 blocks x 256 threads; block handles 32 rows,
// 8 k-chunks of 32 each.
__global__ __launch_bounds__(256) void final_kernel(
    const float* __restrict__ x,       // [N][FEAT]
    const float* __restrict__ outT_t,  // [D][N]
    const float* __restrict__ w,       // [FEAT+D]
    const float* __restrict__ bia,     // [1]
    float* __restrict__ out)           // [N]
{
    const int rl = threadIdx.x & 31;
    const int c  = threadIdx.x >> 5;          // 0..7
    const int r  = blockIdx.x * 32 + rl;

    float acc = 0.f;
    const int k0 = c * 32;
#pragma unroll 8
    for (int kk = 0; kk < 32; ++kk) {
        const int k = k0 + kk;
        acc = fmaf(outT_t[k * N + r], w[FEAT + k], acc);
    }
    __shared__ float part[8][32];
    part[c][rl] = acc;
    __syncthreads();
    if (threadIdx.x < 32) {
        float s = bia[0];
#pragma unroll
        for (int cc = 0; cc < 8; ++cc) s += part[cc][rl];
#pragma unroll
        for (int f = 0; f < FEAT; ++f)
            s = fmaf(x[r * FEAT + f], w[f], s);
        out[r] = 1.f / (1.f + EXP2(-s * LOG2E));
    }
}

extern "C" void kernel_launch(void* const* d_in, const int* in_sizes, int n_in,
                              void* d_out, int out_size, void* d_ws, size_t ws_size,
                              hipStream_t stream) {
    const float* x  = (const float*)d_in[0];
    const float* T  = (const float*)d_in[1];
    const float* w  = (const float*)d_in[2];
    const float* b  = (const float*)d_in[3];
    float* out      = (float*)d_out;
    float* outT_t   = (float*)d_ws;    // D*N floats = 1 MB

    column_kernel<<<dim3(D), dim3(NB), 0, stream>>>(x, T, outT_t);
    final_kernel<<<dim3(N / 32), dim3(256), 0, stream>>>(x, outT_t, w, b, out);
}

// Round 4
// 15.400 us; speedup vs baseline: 3.7405x; 1.1068x over previous
//
#include <hip/hip_runtime.h>
#include <math.h>

#define N    1024
#define FEAT 16
#define D    256
#define NB   1024         // value buckets (== blockDim of column kernel)
#define LOG2E 1.4426950408889634f

#if defined(__has_builtin)
#  if __has_builtin(__builtin_amdgcn_exp2f)
#    define EXP2(x) __builtin_amdgcn_exp2f(x)
#  else
#    define EXP2(x) exp2f(x)
#  endif
#else
#  define EXP2(x) exp2f(x)
#endif

// One block per column k, 1024 threads, 1 element each.
// out[i] = sum_j exp(-|u_i - u_j|), u = Ms[:,k] pre-scaled by log2(e).
// 1024 value-buckets; cross-bucket terms exact via fused prefix(2^u) /
// suffix(2^-u) scans; same-bucket pairs approximated one-sided
// (|err| <= e^dw - e^-dw per pair, dw = bucket width ~= 0.004 nats).
__global__ __launch_bounds__(1024) void column_kernel(
    const float* __restrict__ x,      // [N][FEAT]
    const float* __restrict__ T,      // [FEAT][D]
    float* __restrict__ outT_t)       // [D][N]
{
    const int k = blockIdx.x;
    const int t = threadIdx.x;
    const int lane = t & 63;
    const int wid  = t >> 6;          // 0..15

    __shared__ float2 Sxy[NB];        // (.x = Sx[t], .y = Sn[NB-1-t])  8 KB
    __shared__ float2 P2[NB];         // fused inclusive scans           8 KB
    __shared__ float2 wsum[16];
    __shared__ float  red[32];        // 16 wave-mins + 16 wave-maxs

    Sxy[t] = make_float2(0.f, 0.f);

    // ---- Phase 1: u = (x[t,:] . T[:,k]) * log2e ----
    float tc[FEAT];
#pragma unroll
    for (int f = 0; f < FEAT; ++f) tc[f] = T[f * D + k];

    const float4* xr = (const float4*)(x + t * FEAT);
    float4 a0 = xr[0], a1 = xr[1], a2 = xr[2], a3 = xr[3];
    float dot = 0.f;
    dot = fmaf(a0.x, tc[0],  dot); dot = fmaf(a0.y, tc[1],  dot);
    dot = fmaf(a0.z, tc[2],  dot); dot = fmaf(a0.w, tc[3],  dot);
    dot = fmaf(a1.x, tc[4],  dot); dot = fmaf(a1.y, tc[5],  dot);
    dot = fmaf(a1.z, tc[6],  dot); dot = fmaf(a1.w, tc[7],  dot);
    dot = fmaf(a2.x, tc[8],  dot); dot = fmaf(a2.y, tc[9],  dot);
    dot = fmaf(a2.z, tc[10], dot); dot = fmaf(a2.w, tc[11], dot);
    dot = fmaf(a3.x, tc[12], dot); dot = fmaf(a3.y, tc[13], dot);
    dot = fmaf(a3.z, tc[14], dot); dot = fmaf(a3.w, tc[15], dot);
    const float u = dot * LOG2E;

    // wave min/max
    float mn = u, mx = u;
#pragma unroll
    for (int m = 1; m < 64; m <<= 1) {
        mn = fminf(mn, __shfl_xor(mn, m));
        mx = fmaxf(mx, __shfl_xor(mx, m));
    }
    if (lane == 0) { red[wid] = mn; red[16 + wid] = mx; }
    __syncthreads();                                   // B1: zero-init + red

    float lo = red[0], hi = red[16];
#pragma unroll
    for (int w2 = 1; w2 < 16; ++w2) {
        lo = fminf(lo, red[w2]);
        hi = fmaxf(hi, red[16 + w2]);
    }
    const float range = hi - lo;
    const float invh  = (range > 1e-20f) ? ((float)NB / range) * (1.f - 4e-7f) : 0.f;

    // ---- Phase 2: bucket + per-bucket exp sums ----
    int b = (int)((u - lo) * invh);
    b = max(0, min(b, NB - 1));
    const float ea = EXP2(u);       // e^{Ms}
    const float eb = EXP2(-u);      // e^{-Ms}
    atomicAdd(&Sxy[b].x, ea);
    atomicAdd(&Sxy[NB - 1 - b].y, eb);   // Sn stored reversed
    __syncthreads();                                   // B2: sums complete

    // ---- Phase 3: fused inclusive scan of (Sx, Sn_rev), shfl-based ----
    float2 v = Sxy[t];
    float sx = v.x, sy = v.y;
#pragma unroll
    for (int d2 = 1; d2 < 64; d2 <<= 1) {
        float ox = __shfl_up(sx, d2, 64);
        float oy = __shfl_up(sy, d2, 64);
        if (lane >= d2) { sx += ox; sy += oy; }
    }
    if (lane == 63) wsum[wid] = make_float2(sx, sy);
    __syncthreads();                                   // B3: wave sums ready

    float offx = 0.f, offy = 0.f;
#pragma unroll
    for (int w2 = 0; w2 < 15; ++w2) {
        if (w2 < wid) { offx += wsum[w2].x; offy += wsum[w2].y; }
    }
    P2[t] = make_float2(sx + offx, sy + offy);
    __syncthreads();                                   // B4: scans ready

    // ---- Phase 4: combine ----
    // FWD[b] = incl prefix of Sx at b; SUF[b] = incl suffix of Sn at b.
    const float FWD = P2[b].x;
    const float SUF = P2[NB - 1 - b].y;
    const float Snb = Sxy[NB - 1 - b].y;
    const float o = fmaf(eb, FWD - ea, fmaf(ea, SUF - Snb, 1.f));
    outT_t[k * N + t] = o;
}

// Fused fc + sigmoid. Grid 32 blocks x 256 threads; block handles 32 rows,
// 8 k-chunks of 32 each.
__global__ __launch_bounds__(256) void final_kernel(
    const float* __restrict__ x,       // [N][FEAT]
    const float* __restrict__ outT_t,  // [D][N]
    const float* __restrict__ w,       // [FEAT+D]
    const float* __restrict__ bia,     // [1]
    float* __restrict__ out)           // [N]
{
    const int rl = threadIdx.x & 31;
    const int c  = threadIdx.x >> 5;          // 0..7
    const int r  = blockIdx.x * 32 + rl;

    float acc = 0.f;
    const int k0 = c * 32;
#pragma unroll 8
    for (int kk = 0; kk < 32; ++kk) {
        const int k = k0 + kk;
        acc = fmaf(outT_t[k * N + r], w[FEAT + k], acc);
    }
    __shared__ float part[8][32];
    part[c][rl] = acc;
    __syncthreads();
    if (threadIdx.x < 32) {
        float s = bia[0];
#pragma unroll
        for (int cc = 0; cc < 8; ++cc) s += part[cc][rl];
#pragma unroll
        for (int f = 0; f < FEAT; ++f)
            s = fmaf(x[r * FEAT + f], w[f], s);
        out[r] = 1.f / (1.f + EXP2(-s * LOG2E));
    }
}

extern "C" void kernel_launch(void* const* d_in, const int* in_sizes, int n_in,
                              void* d_out, int out_size, void* d_ws, size_t ws_size,
                              hipStream_t stream) {
    const float* x  = (const float*)d_in[0];
    const float* T  = (const float*)d_in[1];
    const float* w  = (const float*)d_in[2];
    const float* b  = (const float*)d_in[3];
    float* out      = (float*)d_out;
    float* outT_t   = (float*)d_ws;    // D*N floats = 1 MB

    column_kernel<<<dim3(D), dim3(NB), 0, stream>>>(x, T, outT_t);
    final_kernel<<<dim3(N / 32), dim3(256), 0, stream>>>(x, outT_t, w, b, out);
}